// Round 3
// baseline (887.321 us; speedup 1.0000x reference)
//
#include <hip/hip_runtime.h>

// MoE FFN: top-2 of 8 routed SwiGLU experts + shared expert.
// T=4096 tokens, H=1024, F=2752. fp32 in/out, bf16 MFMA internally.
// R3: m97-style GEMMs (BK=64, global_load_lds width-16, unpadded LDS),
//     runtime ws-plan picks batched expert groups vs per-expert fallback.

#define Hdim 1024
#define Fdim 2752
#define Edim 8
#define Tdim 4096
#define BK 64

typedef unsigned short u16;
typedef __bf16 bf16x8 __attribute__((ext_vector_type(8)));
typedef float f32x4 __attribute__((ext_vector_type(4)));

#define MFMA16(a, b, c) __builtin_amdgcn_mfma_f32_16x16x32_bf16(a, b, c, 0, 0, 0)

__device__ __forceinline__ u16 f2bf(float f) {  // fp32 -> bf16 bits, RNE
  unsigned u = __float_as_uint(f);
  u += 0x7fffu + ((u >> 16) & 1u);
  return (u16)(u >> 16);
}

// async global->LDS, 16B per lane; lds base must be wave-uniform (lane*16 implicit)
__device__ __forceinline__ void gld16(u16* lds, const u16* g) {
  __builtin_amdgcn_global_load_lds((const __attribute__((address_space(1))) void*)g,
                                   (__attribute__((address_space(3))) void*)lds, 16, 0, 0);
}

// ---------- transpose + convert: src[R][C] fp32 -> dst[C][R] bf16 ----------
__global__ __launch_bounds__(256) void transpose_k(const float* __restrict__ src,
                                                   u16* __restrict__ dst, int R, int C) {
  __shared__ float tile[64][65];
  const size_t zoff = (size_t)blockIdx.z * R * C;
  src += zoff; dst += zoff;
  const int r0 = blockIdx.y * 64, c0 = blockIdx.x * 64;
  const int tx = threadIdx.x & 63, ty = threadIdx.x >> 6;
#pragma unroll
  for (int i = 0; i < 16; i++) {
    int row = ty * 16 + i;
    tile[row][tx] = src[(size_t)(r0 + row) * C + (c0 + tx)];
  }
  __syncthreads();
#pragma unroll
  for (int i = 0; i < 16; i++) {
    int crow = ty * 16 + i;
    dst[(size_t)(c0 + crow) * R + (r0 + tx)] = f2bf(tile[tx][crow]);
  }
}

// ---------- gate: exact fp32 softmax top-2, build gather lists; x -> bf16 ----------
__global__ __launch_bounds__(64) void gate_k(const float* __restrict__ x,
                                             const float* __restrict__ gw,
                                             u16* __restrict__ xbf,
                                             int* __restrict__ counts,
                                             int* __restrict__ tok,
                                             float* __restrict__ wt) {
  const int t = blockIdx.x, lane = threadIdx.x;
  const float* xr = x + (size_t)t * Hdim;
  float acc[Edim];
#pragma unroll
  for (int e = 0; e < Edim; e++) acc[e] = 0.f;
  for (int i = 0; i < Hdim / 64; i++) {
    int idx = i * 64 + lane;
    float xv = xr[idx];
    xbf[(size_t)t * Hdim + idx] = f2bf(xv);
#pragma unroll
    for (int e = 0; e < Edim; e++) acc[e] += xv * gw[e * Hdim + idx];
  }
#pragma unroll
  for (int e = 0; e < Edim; e++)
    for (int o = 32; o > 0; o >>= 1) acc[e] += __shfl_xor(acc[e], o, 64);
  if (lane == 0) {
    float m = acc[0];
    for (int e = 1; e < Edim; e++) m = fmaxf(m, acc[e]);
    float p[Edim], ssum = 0.f;
    for (int e = 0; e < Edim; e++) { p[e] = expf(acc[e] - m); ssum += p[e]; }
    int i1 = 0; float l1 = acc[0];
    for (int e = 1; e < Edim; e++) if (acc[e] > l1) { l1 = acc[e]; i1 = e; }
    int i2 = -1; float l2 = -1e30f;
    for (int e = 0; e < Edim; e++) if (e != i1 && acc[e] > l2) { l2 = acc[e]; i2 = e; }
    float s1 = p[i1] / ssum, s2 = p[i2] / ssum;
    float den = s1 + s2 + 1e-20f;
    int p1 = atomicAdd(&counts[i1], 1);
    tok[i1 * Tdim + p1] = t; wt[i1 * Tdim + p1] = s1 / den;
    int p2 = atomicAdd(&counts[i2], 1);
    tok[i2 * Tdim + p2] = t; wt[i2 * Tdim + p2] = s2 / den;
  }
}

__global__ void scan_k(const int* __restrict__ counts, int* __restrict__ offs) {
  if (threadIdx.x == 0) {
    int a = 0;
    for (int e = 0; e < Edim; e++) { offs[e] = a; a += counts[e]; }
    offs[Edim] = a;
  }
}

// ---------- GEMM1: s = silu(X@Wg) * (X@Wu), 128 rows x 64 cols, BK=64 ----------
// 4 waves; wave = 64x32 of both G and U. LDS unpadded (global_load_lds layout).
template <bool GATHER>
__global__ __launch_bounds__(256) void gemm1_k(const u16* __restrict__ xbf,
                                               const u16* __restrict__ wg_t,  // [E][F][H] bf16
                                               const u16* __restrict__ wu_t,
                                               const int* __restrict__ tok_list,
                                               const int* __restrict__ counts,
                                               const int* __restrict__ offs,
                                               u16* __restrict__ s_out,
                                               int e_base) {
  const int e = e_base + blockIdx.z;
  const int nrows = GATHER ? counts[e] : Tdim;
  const int m0 = blockIdx.y * 128;
  if (m0 >= nrows) return;
  const int n0 = blockIdx.x * 64;
  const int srow0 = GATHER ? (offs[e] + m0) : m0;

  __shared__ u16 lA[128 * BK];   // 16 KB
  __shared__ u16 lBG[64 * BK];   // 8 KB
  __shared__ u16 lBU[64 * BK];   // 8 KB

  const int tid = threadIdx.x;
  const int wave = tid >> 6, lane = tid & 63;
  const int lsub = lane >> 3;          // row within 8-row issue
  const int lcol = (lane & 7) * 8;     // elem offset within 64-elem row

  // A: 4 issues/wave (8 rows each): rows wave*32 + j*8 + lsub
  const u16* aSrc[4];
#pragma unroll
  for (int j = 0; j < 4; j++) {
    int r = wave * 32 + j * 8 + lsub;
    int ar = m0 + r; if (ar > nrows - 1) ar = nrows - 1;
    int tokA = GATHER ? tok_list[(size_t)e * Tdim + ar] : ar;
    aSrc[j] = xbf + (size_t)tokA * Hdim + lcol;
  }
  // BG/BU: 2 issues each per wave: rows wave*16 + j*8 + lsub
  const u16* gSrc[2]; const u16* uSrc[2];
  const u16* wgE = wg_t + (size_t)e * Fdim * Hdim;
  const u16* wuE = wu_t + (size_t)e * Fdim * Hdim;
#pragma unroll
  for (int j = 0; j < 2; j++) {
    int r = wave * 16 + j * 8 + lsub;
    gSrc[j] = wgE + (size_t)(n0 + r) * Hdim + lcol;
    uSrc[j] = wuE + (size_t)(n0 + r) * Hdim + lcol;
  }
  u16* aDst = lA + (wave * 32) * BK;
  u16* gDst = lBG + (wave * 16) * BK;
  u16* uDst = lBU + (wave * 16) * BK;

  const int wm = (wave & 1) * 64, wn = (wave >> 1) * 32;
  const int lrow = lane & 15, quad = lane >> 4;

  f32x4 zero = {0.f, 0.f, 0.f, 0.f};
  f32x4 accG[4][2], accU[4][2];
#pragma unroll
  for (int mt = 0; mt < 4; mt++)
#pragma unroll
    for (int nt = 0; nt < 2; nt++) { accG[mt][nt] = zero; accU[mt][nt] = zero; }

  for (int k0 = 0; k0 < Hdim; k0 += BK) {
    __syncthreads();
#pragma unroll
    for (int j = 0; j < 4; j++) gld16(aDst + j * 8 * BK, aSrc[j] + k0);
#pragma unroll
    for (int j = 0; j < 2; j++) {
      gld16(gDst + j * 8 * BK, gSrc[j] + k0);
      gld16(uDst + j * 8 * BK, uSrc[j] + k0);
    }
    __syncthreads();
#pragma unroll
    for (int kk = 0; kk < 2; kk++) {
      const int ko = kk * 32 + quad * 8;
      bf16x8 af[4], bg[2], bu[2];
#pragma unroll
      for (int mt = 0; mt < 4; mt++)
        af[mt] = *(const bf16x8*)(lA + (wm + mt * 16 + lrow) * BK + ko);
#pragma unroll
      for (int nt = 0; nt < 2; nt++) {
        bg[nt] = *(const bf16x8*)(lBG + (wn + nt * 16 + lrow) * BK + ko);
        bu[nt] = *(const bf16x8*)(lBU + (wn + nt * 16 + lrow) * BK + ko);
      }
#pragma unroll
      for (int mt = 0; mt < 4; mt++)
#pragma unroll
        for (int nt = 0; nt < 2; nt++) {
          accG[mt][nt] = MFMA16(af[mt], bg[nt], accG[mt][nt]);
          accU[mt][nt] = MFMA16(af[mt], bu[nt], accU[mt][nt]);
        }
    }
  }
#pragma unroll
  for (int mt = 0; mt < 4; mt++)
#pragma unroll
    for (int nt = 0; nt < 2; nt++)
#pragma unroll
      for (int r = 0; r < 4; r++) {
        int row = wm + mt * 16 + quad * 4 + r;
        if (m0 + row < nrows) {
          float g = accG[mt][nt][r], u = accU[mt][nt][r];
          float sv = g * (1.0f / (1.0f + __expf(-g))) * u;
          s_out[(size_t)(srow0 + row) * Fdim + (n0 + wn + nt * 16 + lrow)] = f2bf(sv);
        }
      }
}

// ---------- GEMM2: Y = s @ Wd; 128x128 tile, BK=64; routed: atomicAdd, shared: store ----------
template <bool GATHER>
__global__ __launch_bounds__(256) void gemm2_k(const u16* __restrict__ s_in,
                                               const u16* __restrict__ wd_t,  // [E][H][F] bf16
                                               const int* __restrict__ tok_list,
                                               const int* __restrict__ counts,
                                               const int* __restrict__ offs,
                                               const float* __restrict__ wt_list,
                                               float* __restrict__ out,
                                               int e_base) {
  const int e = e_base + blockIdx.z;
  const int nrows = GATHER ? counts[e] : Tdim;
  const int m0 = blockIdx.y * 128;
  if (m0 >= nrows) return;
  const int n0 = blockIdx.x * 128;

  __shared__ u16 lA[128 * BK];   // 16 KB
  __shared__ u16 lB[128 * BK];   // 16 KB

  const int tid = threadIdx.x;
  const int wave = tid >> 6, lane = tid & 63;
  const int lsub = lane >> 3;
  const int lcol = (lane & 7) * 8;

  const int sBase = GATHER ? offs[e] : 0;
  const u16* aSrc[4]; const u16* bSrc[4];
  const u16* wdE = wd_t + (size_t)e * Hdim * Fdim;
#pragma unroll
  for (int j = 0; j < 4; j++) {
    int r = wave * 32 + j * 8 + lsub;
    int ar = m0 + r; if (ar > nrows - 1) ar = nrows - 1;
    aSrc[j] = s_in + ((size_t)sBase + ar) * Fdim + lcol;
    bSrc[j] = wdE + (size_t)(n0 + r) * Fdim + lcol;
  }
  u16* aDst = lA + (wave * 32) * BK;
  u16* bDst = lB + (wave * 32) * BK;

  const int wm = (wave & 1) * 64, wn = (wave >> 1) * 64;
  const int lrow = lane & 15, quad = lane >> 4;

  f32x4 zero = {0.f, 0.f, 0.f, 0.f};
  f32x4 acc[4][4];
#pragma unroll
  for (int mt = 0; mt < 4; mt++)
#pragma unroll
    for (int nt = 0; nt < 4; nt++) acc[mt][nt] = zero;

  for (int k0 = 0; k0 < Fdim; k0 += BK) {
    __syncthreads();
#pragma unroll
    for (int j = 0; j < 4; j++) {
      gld16(aDst + j * 8 * BK, aSrc[j] + k0);
      gld16(bDst + j * 8 * BK, bSrc[j] + k0);
    }
    __syncthreads();
#pragma unroll
    for (int kk = 0; kk < 2; kk++) {
      const int ko = kk * 32 + quad * 8;
      bf16x8 af[4], bf[4];
#pragma unroll
      for (int mt = 0; mt < 4; mt++)
        af[mt] = *(const bf16x8*)(lA + (wm + mt * 16 + lrow) * BK + ko);
#pragma unroll
      for (int nt = 0; nt < 4; nt++)
        bf[nt] = *(const bf16x8*)(lB + (wn + nt * 16 + lrow) * BK + ko);
#pragma unroll
      for (int mt = 0; mt < 4; mt++)
#pragma unroll
        for (int nt = 0; nt < 4; nt++)
          acc[mt][nt] = MFMA16(af[mt], bf[nt], acc[mt][nt]);
    }
  }
#pragma unroll
  for (int mt = 0; mt < 4; mt++)
#pragma unroll
    for (int nt = 0; nt < 4; nt++)
#pragma unroll
      for (int r = 0; r < 4; r++) {
        int row = wm + mt * 16 + quad * 4 + r;
        if (m0 + row < nrows) {
          int col = n0 + wn + nt * 16 + lrow;
          float v = acc[mt][nt][r];
          if (GATHER) {
            int t = tok_list[(size_t)e * Tdim + m0 + row];
            float w = wt_list[(size_t)e * Tdim + m0 + row];
            atomicAdd(out + (size_t)t * Hdim + col, v * w);
          } else {
            out[(size_t)(m0 + row) * Hdim + col] = v;
          }
        }
      }
}

// ---------------- launch ----------------
extern "C" void kernel_launch(void* const* d_in, const int* in_sizes, int n_in,
                              void* d_out, int out_size, void* d_ws, size_t ws_size,
                              hipStream_t stream) {
  const float* x      = (const float*)d_in[0];
  const float* gate_w = (const float*)d_in[1];
  const float* wg     = (const float*)d_in[2];
  const float* wu     = (const float*)d_in[3];
  const float* wd     = (const float*)d_in[4];
  const float* sg     = (const float*)d_in[5];
  const float* su     = (const float*)d_in[6];
  const float* sd     = (const float*)d_in[7];
  float* out = (float*)d_out;
  char* ws = (char*)d_ws;

  const size_t HFe  = (size_t)Hdim * Fdim;      // elems per weight matrix
  const size_t TF2  = (size_t)Tdim * Fdim * 2;  // one s buffer, bytes

  constexpr size_t O_COUNTS = 0;    // 64 B
  constexpr size_t O_ZOFF   = 64;   // zeros (per-expert mode offs)
  constexpr size_t O_OFFS   = 128;
  constexpr size_t O_TOK    = 1024;
  const size_t O_WT  = O_TOK + (size_t)Edim * Tdim * 4;
  const size_t O_XBF = O_WT + (size_t)Edim * Tdim * 4;
  const size_t O_S   = O_XBF + (size_t)Tdim * Hdim * 2;

  int*   counts = (int*)(ws + O_COUNTS);
  int*   zoff   = (int*)(ws + O_ZOFF);
  int*   offs   = (int*)(ws + O_OFFS);
  int*   tok    = (int*)(ws + O_TOK);
  float* wt     = (float*)(ws + O_WT);
  u16*   xbf    = (u16*)(ws + O_XBF);

  hipMemsetAsync(ws, 0, O_TOK, stream);
  gate_k<<<Tdim, 64, 0, stream>>>(x, gate_w, xbf, counts, tok, wt);
  scan_k<<<1, 64, 0, stream>>>(counts, offs);

  const dim3 blk(256);
  const int GY1 = Tdim / 128;  // 32
  const int GX1 = Fdim / 64;   // 43
  const int GX2 = Hdim / 128;  // 8

  // pick largest expert-group g with pool = 2g matrices fitting after s buffers
  int g = 0;
  for (int cand = 8; cand >= 1; cand >>= 1)
    if (ws_size >= O_S + 3 * TF2 + (size_t)2 * cand * HFe * 2) { g = cand; break; }

  if (g > 0) {
    // ---------------- grouped-batched path ----------------
    u16* S_rt = (u16*)(ws + O_S);              // [2T][F]
    u16* S_sh = S_rt + 2ull * Tdim * Fdim;     // [T][F]
    u16* P    = (u16*)(ws + O_S + 3 * TF2);    // pool: 2g weight matrices

    // shared gemm1
    transpose_k<<<dim3(Fdim / 64, Hdim / 64, 1), blk, 0, stream>>>(sg, P, Hdim, Fdim);
    transpose_k<<<dim3(Fdim / 64, Hdim / 64, 1), blk, 0, stream>>>(su, P + HFe, Hdim, Fdim);
    gemm1_k<false><<<dim3(GX1, GY1, 1), blk, 0, stream>>>(
        xbf, P, P + HFe, tok, counts, offs, S_sh, 0);
    // routed gemm1 in groups of g
    for (int e0 = 0; e0 < Edim; e0 += g) {
      transpose_k<<<dim3(Fdim / 64, Hdim / 64, g), blk, 0, stream>>>(wg + e0 * HFe, P, Hdim, Fdim);
      transpose_k<<<dim3(Fdim / 64, Hdim / 64, g), blk, 0, stream>>>(wu + e0 * HFe, P + (size_t)g * HFe, Hdim, Fdim);
      gemm1_k<true><<<dim3(GX1, GY1, g), blk, 0, stream>>>(
          xbf, P - e0 * HFe, P + (size_t)g * HFe - e0 * HFe, tok, counts, offs, S_rt, e0);
    }
    // shared gemm2 (plain stores init out), then routed gemm2 (atomic)
    transpose_k<<<dim3(Hdim / 64, Fdim / 64, 1), blk, 0, stream>>>(sd, P, Fdim, Hdim);
    gemm2_k<false><<<dim3(GX2, GY1, 1), blk, 0, stream>>>(
        S_sh, P, tok, counts, offs, wt, out, 0);
    for (int e0 = 0; e0 < Edim; e0 += g) {
      transpose_k<<<dim3(Hdim / 64, Fdim / 64, g), blk, 0, stream>>>(wd + e0 * HFe, P, Fdim, Hdim);
      gemm2_k<true><<<dim3(GX2, GY1, g), blk, 0, stream>>>(
          S_rt, P - e0 * HFe, tok, counts, offs, wt, out, e0);
    }
  } else {
    // ---------------- per-expert fallback (~43 MiB) ----------------
    u16* S = (u16*)(ws + O_S);   // [T][F]
    u16* P = S + (size_t)Tdim * Fdim;  // 2 weight matrices

    transpose_k<<<dim3(Fdim / 64, Hdim / 64, 1), blk, 0, stream>>>(sg, P, Hdim, Fdim);
    transpose_k<<<dim3(Fdim / 64, Hdim / 64, 1), blk, 0, stream>>>(su, P + HFe, Hdim, Fdim);
    gemm1_k<false><<<dim3(GX1, GY1, 1), blk, 0, stream>>>(xbf, P, P + HFe, tok, counts, offs, S, 0);
    transpose_k<<<dim3(Hdim / 64, Fdim / 64, 1), blk, 0, stream>>>(sd, P, Fdim, Hdim);
    gemm2_k<false><<<dim3(GX2, GY1, 1), blk, 0, stream>>>(S, P, tok, counts, offs, wt, out, 0);

    for (int e = 0; e < Edim; e++) {
      transpose_k<<<dim3(Fdim / 64, Hdim / 64, 1), blk, 0, stream>>>(wg + e * HFe, P, Hdim, Fdim);
      transpose_k<<<dim3(Fdim / 64, Hdim / 64, 1), blk, 0, stream>>>(wu + e * HFe, P + HFe, Hdim, Fdim);
      gemm1_k<true><<<dim3(GX1, GY1, 1), blk, 0, stream>>>(
          xbf, P - e * HFe, P + HFe - e * HFe, tok, counts, zoff, S, e);
      transpose_k<<<dim3(Hdim / 64, Fdim / 64, 1), blk, 0, stream>>>(wd + e * HFe, P, Fdim, Hdim);
      gemm2_k<true><<<dim3(GX2, GY1, 1), blk, 0, stream>>>(
          S, P - e * HFe, tok, counts, zoff, wt, out, e);
    }
  }

  (void)in_sizes; (void)n_in; (void)out_size; (void)ws_size;
}